// Round 1
// baseline (91.881 us; speedup 1.0000x reference)
//
#include <hip/hip_runtime.h>

// BuzzLoss: per-row exclusive cumprod of (1-conf), weighted sums, negated mean.
// One wave (64 lanes) per row of T=1024. Lane-chunked layout: lane i owns the
// 16 contiguous elements [16i, 16i+16). This needs only ONE 64-lane
// multiplicative scan per row (6 dependent shfl_up steps) instead of 4 chained
// segment scans (24 dependent steps) -- DS-pipe ops per wave drop 44 -> 14.
//
// Score algebra: score = sum(b*a) + (1 - sum(b)) * a_last
//             = sum_lane(sba_lane - a_last*sb_lane) + a_last
// so only ONE butterfly reduction is needed (a_last broadcast first).

#define TLEN 1024
#define CHUNK 16           // elems per lane: 64 lanes * 16 = 1024
#define WAVES_PER_BLOCK 16

__global__ __launch_bounds__(1024)
void buzz_loss_partial(const float* __restrict__ conf,
                       const float* __restrict__ acc,
                       float* __restrict__ partial) {
    const int lane = threadIdx.x & 63;
    const int wave = threadIdx.x >> 6;                 // 0..15
    const long long row = (long long)blockIdx.x * WAVES_PER_BLOCK + wave;

    const float* cbase = conf + row * TLEN + lane * CHUNK;
    const float* abase = acc  + row * TLEN + lane * CHUNK;

    // 8 x dwordx4 loads per wave, issued up front for MLP. Per instruction the
    // wave touches a 4KB span at 64B/lane stride; the 4 k-instructions fill in
    // all bytes of every 64B line, so lines are fetched once and reused in L1.
    float4 cv[4], av[4];
    #pragma unroll
    for (int k = 0; k < 4; ++k) {
        cv[k] = ((const float4*)cbase)[k];
        av[k] = ((const float4*)abase)[k];
    }

    // local product of (1-c) over this lane's 16 elements
    float p = 1.0f;
    #pragma unroll
    for (int k = 0; k < 4; ++k) {
        p *= (1.0f - cv[k].x);
        p *= (1.0f - cv[k].y);
        p *= (1.0f - cv[k].z);
        p *= (1.0f - cv[k].w);
    }

    // single inclusive multiplicative scan across 64 lanes
    float incl = p;
    #pragma unroll
    for (int off = 1; off < 64; off <<= 1) {
        float v = __shfl_up(incl, off, 64);
        if (lane >= off) incl *= v;
    }
    // exclusive prefix: product of (1-c) over all elements before lane*16
    float run = __shfl_up(incl, 1, 64);
    if (lane == 0) run = 1.0f;

    // weighted walk over the lane's 16 elements
    float sba = 0.0f, sb = 0.0f;
#define STEP(CC, AA)                          \
    {                                         \
        float b = (CC) * run;                 \
        sba = fmaf(b, (AA), sba);             \
        sb += b;                              \
        run *= (1.0f - (CC));                 \
    }
    #pragma unroll
    for (int k = 0; k < 4; ++k) {
        STEP(cv[k].x, av[k].x);
        STEP(cv[k].y, av[k].y);
        STEP(cv[k].z, av[k].z);
        STEP(cv[k].w, av[k].w);
    }
#undef STEP

    // acc[row, T-1] lives in lane 63's av[3].w (element 63*16+15 = 1023)
    float alast = __shfl(av[3].w, 63, 64);

    // fold both sums into one butterfly: v = sba - alast*sb
    float v = fmaf(-alast, sb, sba);
    #pragma unroll
    for (int off = 32; off; off >>= 1)
        v += __shfl_xor(v, off, 64);
    float score = v + alast;

    __shared__ float smem[WAVES_PER_BLOCK];
    if (lane == 0) smem[wave] = score;
    __syncthreads();
    if (threadIdx.x == 0) {
        float s = 0.0f;
        #pragma unroll
        for (int w = 0; w < WAVES_PER_BLOCK; ++w) s += smem[w];
        partial[blockIdx.x] = s;
    }
}

// Single-block final reduction: writes d_out directly (no zero-init needed).
__global__ __launch_bounds__(512)
void buzz_loss_reduce(const float* __restrict__ partial, float* __restrict__ out,
                      float neg_inv_b, int n) {
    const int tid = threadIdx.x;                       // 512 threads
    float v = (tid < n) ? partial[tid] : 0.0f;
    #pragma unroll
    for (int off = 32; off; off >>= 1) v += __shfl_xor(v, off, 64);
    __shared__ float smem[8];
    if ((tid & 63) == 0) smem[tid >> 6] = v;
    __syncthreads();
    if (tid == 0) {
        float s = 0.0f;
        #pragma unroll
        for (int w = 0; w < 8; ++w) s += smem[w];
        out[0] = s * neg_inv_b;
    }
}

extern "C" void kernel_launch(void* const* d_in, const int* in_sizes, int n_in,
                              void* d_out, int out_size, void* d_ws, size_t ws_size,
                              hipStream_t stream) {
    const float* conf = (const float*)d_in[0];
    const float* acc  = (const float*)d_in[1];
    float* out = (float*)d_out;
    float* partial = (float*)d_ws;                     // 512 floats of scratch

    const int total = in_sizes[0];
    const int B = total / TLEN;                        // 8192
    const int blocks = B / WAVES_PER_BLOCK;            // 512

    buzz_loss_partial<<<blocks, 64 * WAVES_PER_BLOCK, 0, stream>>>(conf, acc, partial);
    buzz_loss_reduce<<<1, 512, 0, stream>>>(partial, out, -1.0f / (float)B, blocks);
}